// Round 12
// baseline (340.178 us; speedup 1.0000x reference)
//
#include <hip/hip_runtime.h>
#include <hip/hip_bf16.h>
#include <stdint.h>

// ---------------------------------------------------------------------------
// TernaryExpert: out = TL(gelu(TL(x, w_up)), w_down)
//   TL(x,w) = rmsnorm(x) @ ternary(w)^T
// M = 16384, d_model = 1024, d_ff = 4096. Output f32 [16384,1024].
// GEMM: m201 8-phase port, R12 = R11 MINUS all explicit lgkm waits.
// The compiler emits fine-grained lgkmcnt(N) per consuming MFMA (m97 asm
// evidence), so each MFMA waits only for its own operands and the LDS read
// drain overlaps the MFMA burst. Explicit lgkmcnt(0) (R4-R11) serialized
// them -- the diagnosed 34-38% MfmaUtil plateau.
// 256x256, BK=64, 8 waves (2Mx4N, 128x64/wave), 16x16x32 MFMA, 2 K-tiles/
// iter, dual barriers/phase, one 16KB half-tile staged per phase,
// vmcnt(6)@ph4 / vmcnt(8)@ph8 only (counted publishes, verified R10/R11).
// ---------------------------------------------------------------------------

#define M_ROWS   16384
#define D_MODEL  1024
#define D_FF     4096
#define NW       (D_FF * D_MODEL)

typedef __attribute__((ext_vector_type(8))) short bf16x8;
typedef __attribute__((ext_vector_type(4))) float f32x4;
typedef __attribute__((ext_vector_type(8))) unsigned short u16x8;

__device__ __forceinline__ unsigned short f2bf(float f) {
    unsigned u = __builtin_bit_cast(unsigned, f);
    u += 0x7FFFu + ((u >> 16) & 1u);          // RNE
    return (unsigned short)(u >> 16);
}
__device__ __forceinline__ float bf2f(unsigned short h) {
    return __builtin_bit_cast(float, ((unsigned)h) << 16);
}

__device__ __forceinline__ void gload_lds16(const void* g, void* l) {
    __builtin_amdgcn_global_load_lds(
        (const __attribute__((address_space(1))) void*)g,
        (__attribute__((address_space(3))) void*)l, 16, 0, 0);
}

#define BAR()     __builtin_amdgcn_s_barrier()
#define VMCNT(n)  asm volatile("s_waitcnt vmcnt(" #n ")" ::: "memory")

__device__ __forceinline__ float gelu_fast(float v) {
    float w = v * v;
    float z = v * __builtin_fmaf(w, 0.07135481627f, 1.5957691216f);
    float e = __expf(-z);
    return v / (1.0f + e);
}

// ---------------------------------------------------------------------------
// aux kernels
// ---------------------------------------------------------------------------
__global__ __launch_bounds__(256) void absmean_reduce(const float* __restrict__ w,
                                                      double* __restrict__ asum) {
    const int n4 = NW / 4;
    float s = 0.f;
    const float4* w4 = (const float4*)w;
    for (int i = blockIdx.x * blockDim.x + threadIdx.x; i < n4;
         i += gridDim.x * blockDim.x) {
        float4 v = w4[i];
        s += fabsf(v.x) + fabsf(v.y) + fabsf(v.z) + fabsf(v.w);
    }
    #pragma unroll
    for (int off = 32; off > 0; off >>= 1) s += __shfl_down(s, off);
    __shared__ float sm[4];
    int lane = threadIdx.x & 63, wid = threadIdx.x >> 6;
    if (lane == 0) sm[wid] = s;
    __syncthreads();
    if (threadIdx.x == 0) {
        float t = sm[0] + sm[1] + sm[2] + sm[3];
        atomicAdd(asum, (double)t);
    }
}

__global__ __launch_bounds__(256) void quant_kernel(const float* __restrict__ w,
                                                    const double* __restrict__ asum,
                                                    unsigned short* __restrict__ wq) {
    float thr = (float)(0.5 * (*asum) * (1.0 / (double)NW));
    int i = blockIdx.x * blockDim.x + threadIdx.x;
    float4 v = ((const float4*)w)[i];
    ushort4 o;
    o.x = (fabsf(v.x) > thr) ? (v.x > 0.f ? 0x3F80 : 0xBF80) : 0;
    o.y = (fabsf(v.y) > thr) ? (v.y > 0.f ? 0x3F80 : 0xBF80) : 0;
    o.z = (fabsf(v.z) > thr) ? (v.z > 0.f ? 0x3F80 : 0xBF80) : 0;
    o.w = (fabsf(v.w) > thr) ? (v.w > 0.f ? 0x3F80 : 0xBF80) : 0;
    ((ushort4*)wq)[i] = o;
}

__global__ __launch_bounds__(256) void rmsnorm_x(const float* __restrict__ x,
                                                 unsigned short* __restrict__ xn) {
    const int row = blockIdx.x;
    const float4* xr = (const float4*)(x + (size_t)row * D_MODEL);
    float4 v = xr[threadIdx.x];
    float ss = v.x * v.x + v.y * v.y + v.z * v.z + v.w * v.w;
    #pragma unroll
    for (int off = 32; off > 0; off >>= 1) ss += __shfl_down(ss, off);
    __shared__ float sm[4];
    int lane = threadIdx.x & 63, wid = threadIdx.x >> 6;
    if (lane == 0) sm[wid] = ss;
    __syncthreads();
    float tot = sm[0] + sm[1] + sm[2] + sm[3];
    float s = 1.0f / (sqrtf(tot) * (1.0f / 32.0f) + 1e-8f);
    ushort4 o;
    o.x = f2bf(v.x * s); o.y = f2bf(v.y * s);
    o.z = f2bf(v.z * s); o.w = f2bf(v.w * s);
    ((ushort4*)(xn + (size_t)row * D_MODEL))[threadIdx.x] = o;
}

__global__ __launch_bounds__(256) void rowscale_h(const unsigned short* __restrict__ h,
                                                  float* __restrict__ rs) {
    const int row = blockIdx.x;
    const u16x8* hr = (const u16x8*)(h + (size_t)row * D_FF);
    u16x8 a = hr[threadIdx.x * 2 + 0];
    u16x8 b = hr[threadIdx.x * 2 + 1];
    float ss = 0.f;
    #pragma unroll
    for (int j = 0; j < 8; ++j) { float f = bf2f(a[j]); ss += f * f; }
    #pragma unroll
    for (int j = 0; j < 8; ++j) { float f = bf2f(b[j]); ss += f * f; }
    #pragma unroll
    for (int off = 32; off > 0; off >>= 1) ss += __shfl_down(ss, off);
    __shared__ float sm[4];
    int lane = threadIdx.x & 63, wid = threadIdx.x >> 6;
    if (lane == 0) sm[wid] = ss;
    __syncthreads();
    if (threadIdx.x == 0) {
        float tot = sm[0] + sm[1] + sm[2] + sm[3];
        rs[row] = 1.0f / (sqrtf(tot) * (1.0f / 64.0f) + 1e-8f);
    }
}

// ---------------------------------------------------------------------------
// GEMM: C[m][n] = sum_k A[m,k]*B[n,k]   (both K-contiguous)
// LDS slot s = tile&1 at s*65536: A quarters @ q*8192, B @32768 + q*8192.
// ---------------------------------------------------------------------------
template <int EPI, int KDIM, int NBLKN>
__global__ __launch_bounds__(512, 2) void gemm8n(const unsigned short* __restrict__ A,
                                                 const unsigned short* __restrict__ B,
                                                 unsigned short* __restrict__ Cbf,
                                                 float* __restrict__ Cf,
                                                 const float* __restrict__ rowscale,
                                                 int nwg) {
    constexpr int NT = KDIM / 64;
    __shared__ char smem[131072];

    const int tid = threadIdx.x;
    const int bid = blockIdx.x;
    const int swz = (bid & 7) * (nwg >> 3) + (bid >> 3);
    const uint m0 = (uint)(swz / NBLKN) * 256u;
    const uint n0 = (uint)(swz % NBLKN) * 256u;

    const int lane = tid & 63;
    const int wid  = tid >> 6;
    const int wm   = wid >> 2;                  // 0..1 -> 128-row slice
    const int wn   = wid & 3;                   // 0..3 -> 64-col slice
    const int lr   = lane & 15;
    const int lk   = lane >> 4;

    // staging: thread covers row (tid>>3) of a 64-row quarter, chunk tid&7,
    // pre-swizzled source (proven 0-conflict layout, R4..R11)
    const uint rowBase = (uint)(tid >> 3);
    const uint colE = (((uint)(tid & 7) << 4) ^ ((rowBase & 7u) << 4)) >> 1;
    const uint aBase = (m0 + rowBase) * (uint)KDIM + colE;
    const uint bBase = (n0 + rowBase) * (uint)KDIM + colE;
    const uint dstOff = (uint)tid * 16u;

    // fragment read offsets
    const uint xorv = ((uint)(lr & 7)) << 4;
    const uint kb0 = (((uint)lk << 4)      ) ^ xorv;
    const uint kb1 = (((uint)lk << 4) | 64u) ^ xorv;
    uint offA[8], offB[4];
    #pragma unroll
    for (int i = 0; i < 8; ++i)
        offA[i] = (uint)(wm * 128 + i * 16 + lr) * 128u;
    #pragma unroll
    for (int i = 0; i < 4; ++i)
        offB[i] = 32768u + (uint)(wn * 64 + i * 16 + lr) * 128u;

    f32x4 acc[8][4];
    #pragma unroll
    for (int mi = 0; mi < 8; ++mi)
        #pragma unroll
        for (int ni = 0; ni < 4; ++ni)
            acc[mi][ni] = (f32x4){0.f, 0.f, 0.f, 0.f};

    // ---- prologue: stage tiles 0 (slot0) and 1 (slot1), 16 gloads ----
    {
        char* s0 = smem;
        char* s1 = smem + 65536;
        gload_lds16(A + aBase +   0u * KDIM, s0 +     0 + dstOff);   // A q0
        gload_lds16(A + aBase + 128u * KDIM, s0 + 16384 + dstOff);   // A q2
        gload_lds16(B + bBase +   0u * KDIM, s0 + 32768 +     0 + dstOff);
        gload_lds16(B + bBase +  64u * KDIM, s0 + 32768 +  8192 + dstOff);
        gload_lds16(A + aBase +  64u * KDIM, s0 +  8192 + dstOff);   // A q1
        gload_lds16(A + aBase + 192u * KDIM, s0 + 24576 + dstOff);   // A q3
        gload_lds16(B + bBase + 128u * KDIM, s0 + 32768 + 16384 + dstOff);
        gload_lds16(B + bBase + 192u * KDIM, s0 + 32768 + 24576 + dstOff);
        gload_lds16(A + aBase +   0u * KDIM + 64u, s1 +     0 + dstOff);
        gload_lds16(A + aBase + 128u * KDIM + 64u, s1 + 16384 + dstOff);
        gload_lds16(B + bBase +   0u * KDIM + 64u, s1 + 32768 +     0 + dstOff);
        gload_lds16(B + bBase +  64u * KDIM + 64u, s1 + 32768 +  8192 + dstOff);
        gload_lds16(A + aBase +  64u * KDIM + 64u, s1 +  8192 + dstOff);
        gload_lds16(A + aBase + 192u * KDIM + 64u, s1 + 24576 + dstOff);
        gload_lds16(B + bBase + 128u * KDIM + 64u, s1 + 32768 + 16384 + dstOff);
        gload_lds16(B + bBase + 192u * KDIM + 64u, s1 + 32768 + 24576 + dstOff);
    }
    VMCNT(8);            // tile 0 landed; tile 1 (8) in flight
    BAR();

#define MFMA16(MB, NB, AV0, AV1, BV0, BV1)                                     \
    __builtin_amdgcn_s_setprio(1);                                             \
    _Pragma("unroll")                                                          \
    for (int mi = 0; mi < 4; ++mi)                                             \
        _Pragma("unroll")                                                      \
        for (int ni = 0; ni < 2; ++ni)                                         \
            acc[(MB) + mi][(NB) + ni] = __builtin_amdgcn_mfma_f32_16x16x32_bf16(\
                AV0[mi], BV0[ni], acc[(MB) + mi][(NB) + ni], 0, 0, 0);         \
    _Pragma("unroll")                                                          \
    for (int mi = 0; mi < 4; ++mi)                                             \
        _Pragma("unroll")                                                      \
        for (int ni = 0; ni < 2; ++ni)                                         \
            acc[(MB) + mi][(NB) + ni] = __builtin_amdgcn_mfma_f32_16x16x32_bf16(\
                AV1[mi], BV1[ni], acc[(MB) + mi][(NB) + ni], 0, 0, 0);         \
    __builtin_amdgcn_s_setprio(0);

    #pragma unroll 1
    for (int it = 0; it < NT / 2; ++it) {
        const int T = it * 2;
        const char* c0 = smem;
        const char* c1 = smem + 65536;
        char* s0 = smem;
        char* s1 = smem + 65536;
        const bool doS = (T + 2 < NT);
        const uint k2 = (uint)(T + 2) * 64u;
        const uint k3 = (uint)(T + 3) * 64u;
        bf16x8 av0[4], av1[4], bc0k0[2], bc0k1[2], bc1k0[2], bc1k1[2];

        // ===== ph1: tile T, Q0 (A-h0 x B-c0); 12 reads =====
        #pragma unroll
        for (int i = 0; i < 4; ++i) {
            av0[i] = *(const bf16x8*)(c0 + offA[i] + kb0);
            av1[i] = *(const bf16x8*)(c0 + offA[i] + kb1);
        }
        #pragma unroll
        for (int i = 0; i < 2; ++i) {
            bc0k0[i] = *(const bf16x8*)(c0 + offB[i] + kb0);
            bc0k1[i] = *(const bf16x8*)(c0 + offB[i] + kb1);
        }
        BAR();
        MFMA16(0, 0, av0, av1, bc0k0, bc0k1)
        BAR();

        // ===== ph2: Q1 (A-h0 regs x B-c1); 4 reads; stage A{q0,q2}(T+2) =====
        #pragma unroll
        for (int i = 0; i < 2; ++i) {
            bc1k0[i] = *(const bf16x8*)(c0 + offB[2 + i] + kb0);
            bc1k1[i] = *(const bf16x8*)(c0 + offB[2 + i] + kb1);
        }
        if (doS) {
            gload_lds16(A + aBase +   0u * KDIM + k2, s0 +     0 + dstOff);
            gload_lds16(A + aBase + 128u * KDIM + k2, s0 + 16384 + dstOff);
        }
        BAR();
        MFMA16(0, 2, av0, av1, bc1k0, bc1k1)
        BAR();

        // ===== ph3: Q3 (A-h1 x B-c1 regs); 8 reads; stage B-h0(T+2) =====
        #pragma unroll
        for (int i = 0; i < 4; ++i) {
            av0[i] = *(const bf16x8*)(c0 + offA[4 + i] + kb0);
            av1[i] = *(const bf16x8*)(c0 + offA[4 + i] + kb1);
        }
        if (doS) {
            gload_lds16(B + bBase +   0u * KDIM + k2, s0 + 32768 +    0 + dstOff);
            gload_lds16(B + bBase +  64u * KDIM + k2, s0 + 32768 + 8192 + dstOff);
        }
        BAR();
        MFMA16(4, 2, av0, av1, bc1k0, bc1k1)
        BAR();

        // ===== ph4: Q2 (A-h1 regs x B-c0 regs); stage A{q1,q3}(T+2); vmcnt =====
        if (doS) {
            gload_lds16(A + aBase +  64u * KDIM + k2, s0 +  8192 + dstOff);
            gload_lds16(A + aBase + 192u * KDIM + k2, s0 + 24576 + dstOff);
        }
        BAR();
        MFMA16(4, 0, av0, av1, bc0k0, bc0k1)
        if (doS) { VMCNT(6); } else { VMCNT(0); }   // tile T+1 fully landed
        BAR();

        // ===== ph5: tile T+1, Q0; 12 reads; stage B-h1(T+2) =====
        #pragma unroll
        for (int i = 0; i < 4; ++i) {
            av0[i] = *(const bf16x8*)(c1 + offA[i] + kb0);
            av1[i] = *(const bf16x8*)(c1 + offA[i] + kb1);
        }
        #pragma unroll
        for (int i = 0; i < 2; ++i) {
            bc0k0[i] = *(const bf16x8*)(c1 + offB[i] + kb0);
            bc0k1[i] = *(const bf16x8*)(c1 + offB[i] + kb1);
        }
        if (doS) {
            gload_lds16(B + bBase + 128u * KDIM + k2, s0 + 32768 + 16384 + dstOff);
            gload_lds16(B + bBase + 192u * KDIM + k2, s0 + 32768 + 24576 + dstOff);
        }
        BAR();
        MFMA16(0, 0, av0, av1, bc0k0, bc0k1)
        BAR();

        // ===== ph6: Q1; 4 reads; stage A{q0,q2}(T+3) =====
        #pragma unroll
        for (int i = 0; i < 2; ++i) {
            bc1k0[i] = *(const bf16x8*)(c1 + offB[2 + i] + kb0);
            bc1k1[i] = *(const bf16x8*)(c1 + offB[2 + i] + kb1);
        }
        if (doS) {
            gload_lds16(A + aBase +   0u * KDIM + k3, s1 +     0 + dstOff);
            gload_lds16(A + aBase + 128u * KDIM + k3, s1 + 16384 + dstOff);
        }
        BAR();
        MFMA16(0, 2, av0, av1, bc1k0, bc1k1)
        BAR();

        // ===== ph7: Q3; 8 reads; stage B-h0(T+3) =====
        #pragma unroll
        for (int i = 0; i < 4; ++i) {
            av0[i] = *(const bf16x8*)(c1 + offA[4 + i] + kb0);
            av1[i] = *(const bf16x8*)(c1 + offA[4 + i] + kb1);
        }
        if (doS) {
            gload_lds16(B + bBase +   0u * KDIM + k3, s1 + 32768 +    0 + dstOff);
            gload_lds16(B + bBase +  64u * KDIM + k3, s1 + 32768 + 8192 + dstOff);
        }
        BAR();
        MFMA16(4, 2, av0, av1, bc1k0, bc1k1)
        BAR();

        // ===== ph8: Q2; stage A{q1,q3}(T+3) + B-h1(T+3); vmcnt(8) =====
        if (doS) {
            gload_lds16(A + aBase +  64u * KDIM + k3, s1 +  8192 + dstOff);
            gload_lds16(A + aBase + 192u * KDIM + k3, s1 + 24576 + dstOff);
            gload_lds16(B + bBase + 128u * KDIM + k3, s1 + 32768 + 16384 + dstOff);
            gload_lds16(B + bBase + 192u * KDIM + k3, s1 + 32768 + 24576 + dstOff);
        }
        BAR();
        MFMA16(4, 0, av0, av1, bc0k0, bc0k1)
        if (doS) { VMCNT(8); }                      // tile T+2 fully landed
        BAR();
    }
#undef MFMA16

    // epilogue: C/D frag mapping col = lane&15, row = (lane>>4)*4 + reg
    constexpr uint N = (uint)NBLKN * 256u;
    #pragma unroll
    for (int mi = 0; mi < 8; ++mi) {
        #pragma unroll
        for (int j = 0; j < 4; ++j) {
            const uint gr = m0 + (uint)(wm * 128 + mi * 16 + lk * 4 + j);
            float s = 0.f;
            if (EPI == 1) s = rowscale[gr];
            #pragma unroll
            for (int ni = 0; ni < 4; ++ni) {
                const uint gc = n0 + (uint)(wn * 64 + ni * 16 + lr);
                float v = acc[mi][ni][j];
                if (EPI == 0) {
                    Cbf[gr * N + gc] = f2bf(gelu_fast(v));
                } else {
                    Cf[gr * N + gc] = v * s;
                }
            }
        }
    }
}

// ---------------------------------------------------------------------------
extern "C" void kernel_launch(void* const* d_in, const int* in_sizes, int n_in,
                              void* d_out, int out_size, void* d_ws, size_t ws_size,
                              hipStream_t stream) {
    const float* x    = (const float*)d_in[0];
    const float* w_up = (const float*)d_in[1];
    const float* w_dn = (const float*)d_in[2];
    float* out = (float*)d_out;

    uint8_t* ws = (uint8_t*)d_ws;
    unsigned short* h   = (unsigned short*)(ws);                       // 128 MB
    unsigned short* xn  = (unsigned short*)(ws + 134217728);           // 32 MB
    unsigned short* wqu = (unsigned short*)(ws + 134217728 + 33554432);
    unsigned short* wqd = (unsigned short*)(ws + 134217728 + 33554432 + 8388608);
    float*  rs   = (float*)(ws + 134217728 + 33554432 + 2 * 8388608);
    double* alph = (double*)(ws + 134217728 + 33554432 + 2 * 8388608 + 65536);

    hipMemsetAsync(alph, 0, 16, stream);

    absmean_reduce<<<256, 256, 0, stream>>>(w_up, alph + 0);
    absmean_reduce<<<256, 256, 0, stream>>>(w_dn, alph + 1);
    quant_kernel<<<NW / 1024, 256, 0, stream>>>(w_up, alph + 0, wqu);
    quant_kernel<<<NW / 1024, 256, 0, stream>>>(w_dn, alph + 1, wqd);
    rmsnorm_x<<<M_ROWS, 256, 0, stream>>>(x, xn);

    // L1: h = gelu(xn @ wqu^T)  [16384 x 4096], K=1024 -> 64x16 = 1024 blocks
    gemm8n<0, D_MODEL, 16><<<1024, 512, 0, stream>>>(
        xn, wqu, h, nullptr, nullptr, 1024);

    rowscale_h<<<M_ROWS, 256, 0, stream>>>(h, rs);

    // L2: out = (h @ wqd^T) * rs[m]  [16384 x 1024], K=4096 -> 64x4 = 256 blocks
    gemm8n<1, D_FF, 4><<<256, 512, 0, stream>>>(
        h, wqd, nullptr, out, rs, 256);
}

// Round 13
// 228.965 us; speedup vs baseline: 1.4857x; 1.4857x over previous
//
#include <hip/hip_runtime.h>
#include <hip/hip_bf16.h>
#include <stdint.h>

// ---------------------------------------------------------------------------
// TernaryExpert via INT8 MFMA (R13): staged-byte-delivery model says all
// bf16 variants were pinned at ~10.7 B/cy/CU of global->LDS delivery
// (64KB per 256^2 K-tile = 6100cy = the measured plateau). i8 halves the
// bytes per tile (32KB) and doubles MFMA rate: mfma_i32_16x16x64_i8.
// Weights ternary = exact i8. Activations quantized: xq = rn(24*x_norm),
// hq = rn(gelu) (s2=1). i32 accum exact; out = acc * rs[row] with rs
// computed from hq itself.
// GEMM: 256x256, BK=64 (=64B rows), 8 waves (2Mx4N, 128x64/wave), 2 phases,
// 1 barrier/K-tile, triple-buffered 96KB LDS, vmcnt(4) on full-tile-old
// loads only. Swizzle chunk ^= (row>>1)&3 (2-way = free), both sides.
// ---------------------------------------------------------------------------

#define M_ROWS   16384
#define D_MODEL  1024
#define D_FF     4096
#define NW       (D_FF * D_MODEL)

typedef __attribute__((ext_vector_type(4))) int   i32x4;
typedef __attribute__((ext_vector_type(4))) float f32x4;

__device__ __forceinline__ void gload_lds16(const void* g, void* l) {
    __builtin_amdgcn_global_load_lds(
        (const __attribute__((address_space(1))) void*)g,
        (__attribute__((address_space(3))) void*)l, 16, 0, 0);
}

#define BAR()     __builtin_amdgcn_s_barrier()
#define VMCNT(n)  asm volatile("s_waitcnt vmcnt(" #n ")" ::: "memory")

__device__ __forceinline__ float gelu_fast(float v) {
    float w = v * v;
    float z = v * __builtin_fmaf(w, 0.07135481627f, 1.5957691216f);
    float e = __expf(-z);
    return v / (1.0f + e);
}
__device__ __forceinline__ int q8(float v) {
    int q = __float2int_rn(v);
    return (q > 127) ? 127 : ((q < -127) ? -127 : q);
}

// ---------------------------------------------------------------------------
// aux kernels
// ---------------------------------------------------------------------------
__global__ __launch_bounds__(256) void absmean_reduce(const float* __restrict__ w,
                                                      double* __restrict__ asum) {
    const int n4 = NW / 4;
    float s = 0.f;
    const float4* w4 = (const float4*)w;
    for (int i = blockIdx.x * blockDim.x + threadIdx.x; i < n4;
         i += gridDim.x * blockDim.x) {
        float4 v = w4[i];
        s += fabsf(v.x) + fabsf(v.y) + fabsf(v.z) + fabsf(v.w);
    }
    #pragma unroll
    for (int off = 32; off > 0; off >>= 1) s += __shfl_down(s, off);
    __shared__ float sm[4];
    int lane = threadIdx.x & 63, wid = threadIdx.x >> 6;
    if (lane == 0) sm[wid] = s;
    __syncthreads();
    if (threadIdx.x == 0) {
        float t = sm[0] + sm[1] + sm[2] + sm[3];
        atomicAdd(asum, (double)t);
    }
}

// ternarize -> i8 {-1,0,1}, row-major K-contig
__global__ __launch_bounds__(256) void quant_w8(const float* __restrict__ w,
                                                const double* __restrict__ asum,
                                                char* __restrict__ wq) {
    float thr = (float)(0.5 * (*asum) * (1.0 / (double)NW));
    int i = blockIdx.x * blockDim.x + threadIdx.x;   // one float4 -> 4 i8
    float4 v = ((const float4*)w)[i];
    int b0 = (fabsf(v.x) > thr) ? (v.x > 0.f ? 1 : -1) : 0;
    int b1 = (fabsf(v.y) > thr) ? (v.y > 0.f ? 1 : -1) : 0;
    int b2 = (fabsf(v.z) > thr) ? (v.z > 0.f ? 1 : -1) : 0;
    int b3 = (fabsf(v.w) > thr) ? (v.w > 0.f ? 1 : -1) : 0;
    ((int*)wq)[i] = (b0 & 0xff) | ((b1 & 0xff) << 8) |
                    ((b2 & 0xff) << 16) | ((b3 & 0xff) << 24);
}

// rmsnorm + quantize to i8, scale 24
__global__ __launch_bounds__(256) void rmsnorm_xq(const float* __restrict__ x,
                                                  char* __restrict__ xq) {
    const int row = blockIdx.x;
    const float4* xr = (const float4*)(x + (size_t)row * D_MODEL);
    float4 v = xr[threadIdx.x];
    float ss = v.x * v.x + v.y * v.y + v.z * v.z + v.w * v.w;
    #pragma unroll
    for (int off = 32; off > 0; off >>= 1) ss += __shfl_down(ss, off);
    __shared__ float sm[4];
    int lane = threadIdx.x & 63, wid = threadIdx.x >> 6;
    if (lane == 0) sm[wid] = ss;
    __syncthreads();
    float tot = sm[0] + sm[1] + sm[2] + sm[3];
    float s = 24.0f / (sqrtf(tot) * (1.0f / 32.0f) + 1e-8f);
    int b0 = q8(v.x * s), b1 = q8(v.y * s), b2 = q8(v.z * s), b3 = q8(v.w * s);
    ((int*)(xq + (size_t)row * D_MODEL))[threadIdx.x] =
        (b0 & 0xff) | ((b1 & 0xff) << 8) | ((b2 & 0xff) << 16) | ((b3 & 0xff) << 24);
}

// row scale from quantized h (s2=1): rs = 1/(sqrt(sum q^2)/64 + eps)
__global__ __launch_bounds__(256) void rowscale_hq(const char* __restrict__ hq,
                                                   float* __restrict__ rs) {
    const int row = blockIdx.x;
    const int4* hr = (const int4*)(hq + (size_t)row * D_FF);
    int4 d = hr[threadIdx.x];
    float ss = 0.f;
    #pragma unroll
    for (int w = 0; w < 4; ++w) {
        int dw = (w == 0) ? d.x : (w == 1) ? d.y : (w == 2) ? d.z : d.w;
        #pragma unroll
        for (int b = 0; b < 4; ++b) {
            int q = (int)(char)((dw >> (8 * b)) & 0xff);
            ss += (float)(q * q);
        }
    }
    #pragma unroll
    for (int off = 32; off > 0; off >>= 1) ss += __shfl_down(ss, off);
    __shared__ float sm[4];
    int lane = threadIdx.x & 63, wid = threadIdx.x >> 6;
    if (lane == 0) sm[wid] = ss;
    __syncthreads();
    if (threadIdx.x == 0) {
        float tot = sm[0] + sm[1] + sm[2] + sm[3];
        rs[row] = 1.0f / (sqrtf(tot) * (1.0f / 64.0f) + 1e-8f);
    }
}

// ---------------------------------------------------------------------------
// i8 GEMM: C[m][n] = sum_k A[m,k]*B[n,k], A/B i8 K-contig.
// LDS buffer (32KB): A 256x64B @0, B 256x64B @16384. 3 buffers.
// Slot s = tid + inst*512: row = s>>2, chunk16 = s&3; swizzled source
// chunk' = chunk ^ ((row>>1)&3). Reads use the same involution.
// EPI 0: hq = i8(rn(gelu(acc/24)));  EPI 1: out = acc * rs[gr].
// ---------------------------------------------------------------------------
template <int EPI, int KDIM, int NBLKN>
__global__ __launch_bounds__(512, 1) void gemm_i8(const char* __restrict__ A,
                                                  const char* __restrict__ B,
                                                  char* __restrict__ Cq,
                                                  float* __restrict__ Cf,
                                                  const float* __restrict__ rowscale,
                                                  int nwg) {
    constexpr int BUFB = 32768;
    constexpr int NT = KDIM / 64;
    __shared__ char smem[3 * BUFB];

    const int tid = threadIdx.x;
    const int bid = blockIdx.x;
    const int swz = (bid & 7) * (nwg >> 3) + (bid >> 3);
    const uint m0 = (uint)(swz / NBLKN) * 256u;
    const uint n0 = (uint)(swz % NBLKN) * 256u;

    const int lane = tid & 63;
    const int wid  = tid >> 6;
    const int wm   = wid >> 2;                  // 0..1 -> 128-row slice
    const int wn   = wid & 3;                   // 0..3 -> 64-col slice
    const int lr   = lane & 15;
    const int lk   = lane >> 4;                 // 16B k-chunk 0..3

    // staging source (inverse swizzle), per inst in {0,1}
    uint aOff[2], bOff[2];
    #pragma unroll
    for (int inst = 0; inst < 2; ++inst) {
        uint s = (uint)tid + (uint)inst * 512u;
        uint row = s >> 2, ch = s & 3u;
        uint src = ((ch ^ ((row >> 1) & 3u)) << 4);
        aOff[inst] = (m0 + row) * (uint)KDIM + src;
        bOff[inst] = (n0 + row) * (uint)KDIM + src;
    }
    const uint dstOff = (uint)tid * 16u;

    // fragment read offsets (bytes)
    uint offA[8], offB[4];
    #pragma unroll
    for (int i = 0; i < 8; ++i) {
        uint row = (uint)(wm * 128 + i * 16 + lr);
        offA[i] = row * 64u + (((uint)lk ^ ((row >> 1) & 3u)) << 4);
    }
    #pragma unroll
    for (int i = 0; i < 4; ++i) {
        uint row = (uint)(wn * 64 + i * 16 + lr);
        offB[i] = 16384u + row * 64u + (((uint)lk ^ ((row >> 1) & 3u)) << 4);
    }

    i32x4 acc[8][4];
    #pragma unroll
    for (int mi = 0; mi < 8; ++mi)
        #pragma unroll
        for (int ni = 0; ni < 4; ++ni)
            acc[mi][ni] = (i32x4){0, 0, 0, 0};

    // prologue: stage tiles 0 and 1 (A then B each; 4 insts/tile)
    #pragma unroll
    for (int t = 0; t < 2; ++t) {
        char* sb = smem + t * BUFB;
        const uint k0 = (uint)t * 64u;
        gload_lds16(A + aOff[0] + k0, sb +     0 + dstOff);
        gload_lds16(A + aOff[1] + k0, sb +  8192 + dstOff);
        gload_lds16(B + bOff[0] + k0, sb + 16384 + dstOff);
        gload_lds16(B + bOff[1] + k0, sb + 24576 + dstOff);
    }
    VMCNT(4);            // tile 0 landed; tile 1 in flight
    BAR();

    int cur = 0, stg = 2;
    #pragma unroll 1
    for (int t = 0; t < NT; ++t) {
        const char* cb = smem + cur * BUFB;
        char* sb = smem + stg * BUFB;
        const uint kc = (uint)(t + 2) * 64u;
        const bool doS = (t + 2 < NT);
        i32x4 av[4], bv[4];

        // ---- P1: A-h0 + all B reads; stage A(t+2); 16 MFMA ----
        #pragma unroll
        for (int i = 0; i < 4; ++i) av[i] = *(const i32x4*)(cb + offA[i]);
        #pragma unroll
        for (int i = 0; i < 4; ++i) bv[i] = *(const i32x4*)(cb + offB[i]);
        if (doS) {
            gload_lds16(A + aOff[0] + kc, sb +    0 + dstOff);
            gload_lds16(A + aOff[1] + kc, sb + 8192 + dstOff);
        }
        __builtin_amdgcn_s_setprio(1);
        #pragma unroll
        for (int mi = 0; mi < 4; ++mi)
            #pragma unroll
            for (int ni = 0; ni < 4; ++ni)
                acc[mi][ni] = __builtin_amdgcn_mfma_i32_16x16x64_i8(
                    av[mi], bv[ni], acc[mi][ni], 0, 0, 0);
        __builtin_amdgcn_s_setprio(0);

        // ---- P2: A-h1 reads (B reg-reused); stage B(t+2); 16 MFMA ----
        #pragma unroll
        for (int i = 0; i < 4; ++i) av[i] = *(const i32x4*)(cb + offA[4 + i]);
        if (doS) {
            gload_lds16(B + bOff[0] + kc, sb + 16384 + dstOff);
            gload_lds16(B + bOff[1] + kc, sb + 24576 + dstOff);
        }
        __builtin_amdgcn_s_setprio(1);
        #pragma unroll
        for (int mi = 0; mi < 4; ++mi)
            #pragma unroll
            for (int ni = 0; ni < 4; ++ni)
                acc[4 + mi][ni] = __builtin_amdgcn_mfma_i32_16x16x64_i8(
                    av[mi], bv[ni], acc[4 + mi][ni], 0, 0, 0);
        __builtin_amdgcn_s_setprio(0);

        if (doS) { VMCNT(4); } else { VMCNT(0); }  // tile t+1 fully landed
        BAR();
        cur = (cur == 2) ? 0 : cur + 1;
        stg = (stg == 2) ? 0 : stg + 1;
    }

    // epilogue: C/D frag mapping col = lane&15, row = (lane>>4)*4 + reg
    constexpr uint N = (uint)NBLKN * 256u;
    #pragma unroll
    for (int mi = 0; mi < 8; ++mi) {
        #pragma unroll
        for (int j = 0; j < 4; ++j) {
            const uint gr = m0 + (uint)(wm * 128 + mi * 16 + lk * 4 + j);
            float s = 0.f;
            if (EPI == 1) s = rowscale[gr];
            #pragma unroll
            for (int ni = 0; ni < 4; ++ni) {
                const uint gc = n0 + (uint)(wn * 64 + ni * 16 + lr);
                if (EPI == 0) {
                    float g = gelu_fast((float)acc[mi][ni][j] * (1.0f / 24.0f));
                    Cq[gr * N + gc] = (char)q8(g);
                } else {
                    Cf[gr * N + gc] = (float)acc[mi][ni][j] * s;
                }
            }
        }
    }
}

// ---------------------------------------------------------------------------
extern "C" void kernel_launch(void* const* d_in, const int* in_sizes, int n_in,
                              void* d_out, int out_size, void* d_ws, size_t ws_size,
                              hipStream_t stream) {
    const float* x    = (const float*)d_in[0];
    const float* w_up = (const float*)d_in[1];
    const float* w_dn = (const float*)d_in[2];
    float* out = (float*)d_out;

    uint8_t* ws = (uint8_t*)d_ws;
    char* hq  = (char*)(ws);                                   // 64 MB
    char* xq  = (char*)(ws + 67108864);                        // 16 MB
    char* wqu = (char*)(ws + 67108864 + 16777216);             // 4 MB
    char* wqd = (char*)(ws + 67108864 + 16777216 + 4194304);   // 4 MB
    float*  rs   = (float*)(ws + 67108864 + 16777216 + 2 * 4194304);
    double* alph = (double*)(ws + 67108864 + 16777216 + 2 * 4194304 + 65536);

    hipMemsetAsync(alph, 0, 16, stream);

    absmean_reduce<<<256, 256, 0, stream>>>(w_up, alph + 0);
    absmean_reduce<<<256, 256, 0, stream>>>(w_dn, alph + 1);
    quant_w8<<<NW / 1024, 256, 0, stream>>>(w_up, alph + 0, wqu);
    quant_w8<<<NW / 1024, 256, 0, stream>>>(w_dn, alph + 1, wqd);
    rmsnorm_xq<<<M_ROWS, 256, 0, stream>>>(x, xq);

    // L1: hq = q8(gelu((xq @ wqu^T)/24))  [16384 x 4096], K=1024
    gemm_i8<0, D_MODEL, 16><<<1024, 512, 0, stream>>>(
        xq, wqu, hq, nullptr, nullptr, 1024);

    rowscale_hq<<<M_ROWS, 256, 0, stream>>>(hq, rs);

    // L2: out = (hq @ wqd^T) * rs[m]  [16384 x 1024], K=4096
    gemm_i8<1, D_FF, 4><<<256, 512, 0, stream>>>(
        hq, wqd, nullptr, out, rs, 256);
}